// Round 1
// baseline (474.511 us; speedup 1.0000x reference)
//
#include <hip/hip_runtime.h>
#include <math.h>

#define CH 1024
#define HWSZ 4096   // 64*64
#define NB 16

// Kernel 1: per-(b,c) spatial mean. One block per plane (16384 planes).
__global__ __launch_bounds__(256) void mean_kernel(const float* __restrict__ x,
                                                   float* __restrict__ y) {
    const int plane = blockIdx.x;                 // b*1024 + c
    const float4* xp = (const float4*)x + (size_t)plane * (HWSZ / 4);
    const int tid = threadIdx.x;
    float s = 0.f;
#pragma unroll
    for (int j = 0; j < 4; ++j) {
        float4 v = xp[tid + 256 * j];
        s += (v.x + v.y) + (v.z + v.w);
    }
    // wave64 reduce
#pragma unroll
    for (int off = 32; off > 0; off >>= 1)
        s += __shfl_down(s, off, 64);
    __shared__ float ls[4];
    if ((tid & 63) == 0) ls[tid >> 6] = s;
    __syncthreads();
    if (tid == 0) {
        float t = (ls[0] + ls[1]) + (ls[2] + ls[3]);
        y[plane] = t * (1.f / (float)HWSZ);
    }
}

// Kernel 2: dilated conv (dilation=510, pad=2, K=3) + sigmoid -> s[16*8]
__global__ __launch_bounds__(128) void gate_kernel(const float* __restrict__ y,
                                                   const float* __restrict__ w,
                                                   float* __restrict__ s) {
    const int t = threadIdx.x;  // 0..127 : b*8 + o
    const int b = t >> 3;
    const int o = t & 7;
    const float w0 = w[0], w1 = w[1], w2 = w[2];
    const float* yb = y + b * CH;
    float acc = w1 * yb[o + 508];
    if (o >= 2) acc += w0 * yb[o - 2];
    if (o <= 5) acc += w2 * yb[o + 1018];
    s[t] = 1.f / (1.f + expf(-acc));
}

// Kernel 3: out = x * gate. One float4 per thread; gate is block-uniform.
__global__ __launch_bounds__(256) void mul_kernel(const float* __restrict__ x,
                                                  const float* __restrict__ s,
                                                  float* __restrict__ out) {
    const size_t i = (size_t)blockIdx.x * 256 + threadIdx.x;  // float4 index
    const int plane = (int)(i >> 10);      // 1024 float4 per plane
    const int b = plane >> 10;
    const int c = plane & 1023;
    const float g = s[(b << 3) | (c >> 7)];
    float4 v = ((const float4*)x)[i];
    v.x *= g; v.y *= g; v.z *= g; v.w *= g;
    ((float4*)out)[i] = v;
}

extern "C" void kernel_launch(void* const* d_in, const int* in_sizes, int n_in,
                              void* d_out, int out_size, void* d_ws, size_t ws_size,
                              hipStream_t stream) {
    const float* x = (const float*)d_in[0];
    const float* w = (const float*)d_in[1];
    float* out = (float*)d_out;

    float* y = (float*)d_ws;              // 16*1024 floats
    float* s = y + NB * CH;               // 16*8 floats

    mean_kernel<<<NB * CH, 256, 0, stream>>>(x, y);
    gate_kernel<<<1, 128, 0, stream>>>(y, w, s);
    const size_t nf4 = (size_t)NB * CH * HWSZ / 4;   // 16.78M float4
    mul_kernel<<<(int)(nf4 / 256), 256, 0, stream>>>(x, s, out);
}

// Round 3
// 466.437 us; speedup vs baseline: 1.0173x; 1.0173x over previous
//
#include <hip/hip_runtime.h>
#include <math.h>

#define CH 1024
#define HWSZ 4096   // 64*64
#define NB 16

// Native 16B vector (ext_vector_type) — accepted by __builtin_nontemporal_*.
typedef float vfloat4 __attribute__((ext_vector_type(4)));

// Kernel 1: per-(b,c) spatial mean. One block per plane (16384 planes).
// 256 threads x 4 float4 = 4096 floats = one full plane.
__global__ __launch_bounds__(256) void mean_kernel(const float* __restrict__ x,
                                                   float* __restrict__ y) {
    const int plane = blockIdx.x;                 // b*1024 + c
    const vfloat4* xp = (const vfloat4*)x + (size_t)plane * (HWSZ / 4);
    const int tid = threadIdx.x;
    float s = 0.f;
#pragma unroll
    for (int j = 0; j < 4; ++j) {
        vfloat4 v = xp[tid + 256 * j];
        s += (v.x + v.y) + (v.z + v.w);
    }
    // wave64 down-reduce
#pragma unroll
    for (int off = 32; off > 0; off >>= 1)
        s += __shfl_down(s, off, 64);
    __shared__ float ls[4];
    if ((tid & 63) == 0) ls[tid >> 6] = s;
    __syncthreads();
    if (tid == 0) {
        float t = (ls[0] + ls[1]) + (ls[2] + ls[3]);
        y[plane] = t * (1.f / (float)HWSZ);
    }
}

// Kernel 2 (fused gate + multiply): one block per plane. Every thread
// redundantly computes the block-uniform gate (3 broadcast loads from y,
// 64 KB L2-hot, + sigmoid), then scales its 4 float4.
// Dilated conv: s[b,o] = sigmoid(w0*y[b,o-2]{o>=2} + w1*y[b,o+508]
//                                + w2*y[b,o+1018]{o<=5}),  o = c>>7.
__global__ __launch_bounds__(256) void mul_kernel(const float* __restrict__ x,
                                                  const float* __restrict__ y,
                                                  const float* __restrict__ w,
                                                  float* __restrict__ out) {
    const int plane = blockIdx.x;          // b*1024 + c
    const int b = plane >> 10;
    const int c = plane & 1023;
    const int o = c >> 7;                  // modality group, block-uniform

    const float* yb = y + (b << 10);
    float acc = w[1] * yb[o + 508];
    if (o >= 2) acc += w[0] * yb[o - 2];   // uniform branch, no divergence
    if (o <= 5) acc += w[2] * yb[o + 1018];
    const float g = 1.f / (1.f + __expf(-acc));

    const vfloat4* xp = (const vfloat4*)x + (size_t)plane * (HWSZ / 4);
    vfloat4* op = (vfloat4*)out + (size_t)plane * (HWSZ / 4);
    const int tid = threadIdx.x;
#pragma unroll
    for (int j = 0; j < 4; ++j) {
        vfloat4 v = xp[tid + 256 * j];
        v *= g;
        __builtin_nontemporal_store(v, &op[tid + 256 * j]);
    }
}

extern "C" void kernel_launch(void* const* d_in, const int* in_sizes, int n_in,
                              void* d_out, int out_size, void* d_ws, size_t ws_size,
                              hipStream_t stream) {
    const float* x = (const float*)d_in[0];
    const float* w = (const float*)d_in[1];
    float* out = (float*)d_out;

    float* y = (float*)d_ws;              // 16*1024 floats

    mean_kernel<<<NB * CH, 256, 0, stream>>>(x, y);
    mul_kernel<<<NB * CH, 256, 0, stream>>>(x, y, w, out);
}